// Round 2
// baseline (230.507 us; speedup 1.0000x reference)
//
#include <hip/hip_runtime.h>
#include <cstdint>

// B=16384, D=512, U=512, K=D+U=1024, N=4U=2048
#define HU 8388608  // 16384*512, offset of c-part in out

typedef __attribute__((ext_vector_type(8))) short short8_t;
typedef __attribute__((ext_vector_type(4))) float float4_t;
typedef __attribute__((ext_vector_type(16))) float float16_t;
typedef __attribute__((ext_vector_type(4))) unsigned int uint4_t;
typedef __attribute__((ext_vector_type(2))) unsigned int uint2_t;

__device__ __forceinline__ unsigned short f2bf(float x) {
    unsigned u = __builtin_bit_cast(unsigned, x);
    u += 0x7fffu + ((u >> 16) & 1u);  // RNE
    return (unsigned short)(u >> 16);
}

__device__ __forceinline__ void gll16(const void* g, const void* lds) {
    __builtin_amdgcn_global_load_lds(
        (const __attribute__((address_space(1))) unsigned int*)(uintptr_t)g,
        (__attribute__((address_space(3))) unsigned int*)(unsigned int)(uintptr_t)lds,
        16, 0, 0);
}

__device__ __forceinline__ float sigm(float x) {
    return __builtin_amdgcn_rcpf(1.f + __expf(-x));
}
__device__ __forceinline__ float tanhfast(float x) {
    float ax = fabsf(x);
    float e = __expf(-2.f * ax);
    float r = (1.f - e) * __builtin_amdgcn_rcpf(1.f + e);
    return copysignf(r, x);
}

// ---------- merged pre-pass: blocks [0,8192) concat+cvt, [8192,10240) transpose ----------
__global__ __launch_bounds__(256) void prep(const float* __restrict__ x,
                                            const float* __restrict__ h,
                                            const float* __restrict__ W,
                                            const float* __restrict__ R,
                                            unsigned short* __restrict__ xh,
                                            unsigned short* __restrict__ btw) {
    __shared__ float t[32 * 33];
    int bid = blockIdx.x;
    int tid = threadIdx.x;
    if (bid < 8192) {
        int n = bid * 256 + tid;
        int e8 = n * 8;
        int row = e8 >> 10, col = e8 & 1023;
        const float* src = (col < 512) ? (x + row * 512 + col) : (h + row * 512 + (col - 512));
        float4_t lo = *(const float4_t*)src;
        float4_t hi = *(const float4_t*)(src + 4);
        uint4_t o;
        o.x = (unsigned)f2bf(lo.x) | ((unsigned)f2bf(lo.y) << 16);
        o.y = (unsigned)f2bf(lo.z) | ((unsigned)f2bf(lo.w) << 16);
        o.z = (unsigned)f2bf(hi.x) | ((unsigned)f2bf(hi.y) << 16);
        o.w = (unsigned)f2bf(hi.z) | ((unsigned)f2bf(hi.w) << 16);
        *(uint4_t*)(xh + e8) = o;
    } else {
        // Gate-major layout: Btw[n''][k] = bf16(Wall[k][g*512+u]), n'' = ub*128 + g*32 + uo
        int gid = bid - 8192;
        int kt = gid & 31, ub = (gid >> 5) & 15, g = gid >> 9;
        int ky = tid >> 3, ux4 = (tid & 7) * 4;
        int kg = kt * 32 + ky;
        int col = g * 512 + ub * 32 + ux4;
        const float* src = (kg < 512) ? (W + (size_t)kg * 2048 + col)
                                      : (R + (size_t)(kg - 512) * 2048 + col);
        float4_t v = *(const float4_t*)src;
        t[ky * 33 + ux4 + 0] = v.x;
        t[ky * 33 + ux4 + 1] = v.y;
        t[ky * 33 + ux4 + 2] = v.z;
        t[ky * 33 + ux4 + 3] = v.w;
        __syncthreads();
        int uo = tid >> 3, kx4 = (tid & 7) * 4;
        unsigned short o0 = f2bf(t[(kx4 + 0) * 33 + uo]);
        unsigned short o1 = f2bf(t[(kx4 + 1) * 33 + uo]);
        unsigned short o2 = f2bf(t[(kx4 + 2) * 33 + uo]);
        unsigned short o3 = f2bf(t[(kx4 + 3) * 33 + uo]);
        uint2_t p;
        p.x = (unsigned)o0 | ((unsigned)o1 << 16);
        p.y = (unsigned)o2 | ((unsigned)o3 << 16);
        *(uint2_t*)(btw + (size_t)(ub * 128 + g * 32 + uo) * 1024 + kt * 32 + kx4) = p;
    }
}

// ---------- main: 256x256 tile, BK=32, 8 waves, ring-4, merged 16-MFMA phases ----------
// LDS: A slots [0..3] @ slot*8192 shorts, B slots @ 32768 + slot*8192 (128 KB total).
// Row-pair layout: 128-B LDS rows hold global rows {2rp, 2rp+1}; 16B chunk at position
// s holds global chunk g = s ^ (rp&7), g = 4*parity + c2  (conflict-free reads+writes).
// Pipeline: stage t+3 during t, single vmcnt(8) per tile, 2 barriers/tile.

#define MFMA(va, vb, vc) __builtin_amdgcn_mfma_f32_32x32x16_bf16(va, vb, vc, 0, 0, 0)

#define STAGE(T)                                             \
    do {                                                     \
        int _so = ((T) & 3) * 8192, _ko = (T) * 32;          \
        gll16(aSrc0 + _ko, &lds[_so + dU0]);                 \
        gll16(aSrc1 + _ko, &lds[_so + dU1]);                 \
        gll16(bSrc0 + _ko, &lds[32768 + _so + dU0]);         \
        gll16(bSrc1 + _ko, &lds[32768 + _so + dU1]);         \
    } while (0)

#define TILE(T, DOSTAGE, VM)                                                     \
    do {                                                                         \
        int _o = ((T) & 3) * 8192;                                               \
        short8_t a00 = *(const short8_t*)&lds[_o + aro[0][0]];                   \
        short8_t a10 = *(const short8_t*)&lds[_o + aro[1][0]];                   \
        short8_t b00 = *(const short8_t*)&lds[_o + bro[0][0]];                   \
        short8_t b10 = *(const short8_t*)&lds[_o + bro[1][0]];                   \
        short8_t b20 = *(const short8_t*)&lds[_o + bro[2][0]];                   \
        short8_t b30 = *(const short8_t*)&lds[_o + bro[3][0]];                   \
        short8_t a01 = *(const short8_t*)&lds[_o + aro[0][1]];                   \
        short8_t a11 = *(const short8_t*)&lds[_o + aro[1][1]];                   \
        short8_t b01 = *(const short8_t*)&lds[_o + bro[0][1]];                   \
        short8_t b11 = *(const short8_t*)&lds[_o + bro[1][1]];                   \
        short8_t b21 = *(const short8_t*)&lds[_o + bro[2][1]];                   \
        short8_t b31 = *(const short8_t*)&lds[_o + bro[3][1]];                   \
        if (DOSTAGE) STAGE((T) + 3);                                             \
        asm volatile("s_waitcnt vmcnt(%0)" ::"i"(VM) : "memory");                \
        __builtin_amdgcn_s_barrier();                                            \
        __builtin_amdgcn_s_setprio(1);                                           \
        acc[0][0] = MFMA(a00, b00, acc[0][0]);                                   \
        acc[0][1] = MFMA(a00, b10, acc[0][1]);                                   \
        acc[0][2] = MFMA(a00, b20, acc[0][2]);                                   \
        acc[0][3] = MFMA(a00, b30, acc[0][3]);                                   \
        acc[1][0] = MFMA(a10, b00, acc[1][0]);                                   \
        acc[1][1] = MFMA(a10, b10, acc[1][1]);                                   \
        acc[1][2] = MFMA(a10, b20, acc[1][2]);                                   \
        acc[1][3] = MFMA(a10, b30, acc[1][3]);                                   \
        acc[0][0] = MFMA(a01, b01, acc[0][0]);                                   \
        acc[0][1] = MFMA(a01, b11, acc[0][1]);                                   \
        acc[0][2] = MFMA(a01, b21, acc[0][2]);                                   \
        acc[0][3] = MFMA(a01, b31, acc[0][3]);                                   \
        acc[1][0] = MFMA(a11, b01, acc[1][0]);                                   \
        acc[1][1] = MFMA(a11, b11, acc[1][1]);                                   \
        acc[1][2] = MFMA(a11, b21, acc[1][2]);                                   \
        acc[1][3] = MFMA(a11, b31, acc[1][3]);                                   \
        __builtin_amdgcn_s_setprio(0);                                           \
        __builtin_amdgcn_s_barrier();                                            \
    } while (0)

__global__ __launch_bounds__(512, 2) void lstm_main(
    const unsigned short* __restrict__ xh,   // [16384][1024] bf16
    const unsigned short* __restrict__ btw,  // [2048][1024] bf16, gate-major rows
    const float* __restrict__ c_tm1,         // [16384][512]
    const float* __restrict__ pw,            // [512][3]
    const float* __restrict__ bias,          // [2048]
    float* __restrict__ out)                 // [2][16384][512]
{
    __shared__ __align__(16) short lds[65536];  // 128 KB

    int tid = threadIdx.x;
    int lane = tid & 63, wid = tid >> 6;
    int wrow = wid & 3, wcol = wid >> 2;     // 4 M-waves x 2 N-waves
    int l31 = lane & 31, hfl = lane >> 5;

    // XCD-aware swizzle: each XCD (bid&7) gets a contiguous 8-mb x 8-nb chunk
    int bid = blockIdx.x;
    int xcd = bid & 7, local = bid >> 3;
    int mb = xcd * 8 + (local & 7);          // [0,64)
    int nb = local >> 3;                     // [0,8)

    // ---- staging: per thread 2 A-gll16 + 2 B-gll16 per tile; linear LDS dest,
    //      pre-swizzled per-lane global source (rule #21: same permutation as reads)
    int st0 = wid, st1 = 8 + wid;            // sweep index i*8+wid
    int rp0 = st0 * 8 + (lane >> 3), rp1 = st1 * 8 + (lane >> 3);
    int g0 = (lane & 7) ^ (rp0 & 7), g1 = (lane & 7) ^ (rp1 & 7);
    const unsigned short* aSrc0 = xh + (size_t)(mb * 256 + 2 * rp0 + (g0 >> 2)) * 1024 + (g0 & 3) * 8;
    const unsigned short* aSrc1 = xh + (size_t)(mb * 256 + 2 * rp1 + (g1 >> 2)) * 1024 + (g1 & 3) * 8;
    const unsigned short* bSrc0 = btw + (size_t)(nb * 256 + 2 * rp0 + (g0 >> 2)) * 1024 + (g0 & 3) * 8;
    const unsigned short* bSrc1 = btw + (size_t)(nb * 256 + 2 * rp1 + (g1 >> 2)) * 1024 + (g1 & 3) * 8;
    int dU0 = st0 * 512, dU1 = st1 * 512;    // wave-uniform LDS dest (shorts)

    // ---- read offsets (shorts within slot): frag(r, c2) at rp*64 + s*8,
    //      s = (4*(r&1) + c2) ^ (rp&7), c2 = jj*2 + hfl
    int aro[2][2], bro[4][2];
#pragma unroll
    for (int m = 0; m < 2; ++m) {
        int r = wrow * 64 + m * 32 + l31, rp = r >> 1;
#pragma unroll
        for (int jj = 0; jj < 2; ++jj) {
            int s = (4 * (r & 1) + jj * 2 + hfl) ^ (rp & 7);
            aro[m][jj] = rp * 64 + s * 8;
        }
    }
#pragma unroll
    for (int g = 0; g < 4; ++g) {
        int r = wcol * 128 + g * 32 + l31, rp = r >> 1;
#pragma unroll
        for (int jj = 0; jj < 2; ++jj) {
            int s = (4 * (r & 1) + jj * 2 + hfl) ^ (rp & 7);
            bro[g][jj] = 32768 + rp * 64 + s * 8;
        }
    }

    float16_t acc[2][4];
#pragma unroll
    for (int m = 0; m < 2; ++m)
#pragma unroll
        for (int g = 0; g < 4; ++g)
#pragma unroll
            for (int r = 0; r < 16; ++r) acc[m][g][r] = 0.f;

    // ---- prologue: stage tiles 0,1,2; retire tile 0 (12 in flight -> 8) ----
    STAGE(0);
    STAGE(1);
    STAGE(2);
    asm volatile("s_waitcnt vmcnt(8)" ::: "memory");
    __builtin_amdgcn_s_barrier();

    // ---- main loop: tiles 0..27 stage t+3, vmcnt(8); peeled tail 28..31 ----
#pragma unroll 4
    for (int t = 0; t < 28; ++t) TILE(t, 1, 8);
    TILE(28, 1, 8);   // stages tile 31; retires 29
    TILE(29, 0, 4);   // retires 30
    TILE(30, 0, 0);   // retires 31
    TILE(31, 0, 0);

    // ---- register epilogue: lane holds all 4 gates of (row, unit) in acc[m][0..3] ----
    // 32x32 C/D: col=lane&31 (unit), row=(reg&3)+8*(reg>>2)+4*(lane>>5)
    int u = nb * 64 + wcol * 32 + l31;
    float bi = bias[u], bf = bias[512 + u], bg2 = bias[1024 + u], bo2 = bias[1536 + u];
    float pwi = pw[u * 3 + 0], pwf = pw[u * 3 + 1], pwo = pw[u * 3 + 2];
    int rbase = mb * 256 + wrow * 64 + 4 * hfl;
#pragma unroll
    for (int m = 0; m < 2; ++m) {
#pragma unroll
        for (int reg = 0; reg < 16; ++reg) {
            int grow = rbase + m * 32 + (reg & 3) + 8 * (reg >> 2);
            size_t off = (size_t)grow * 512 + u;
            float c1 = c_tm1[off];
            float iv = sigm(acc[m][0][reg] + bi + c1 * pwi);
            float fv = sigm(acc[m][1][reg] + bf + c1 * pwf);
            float gv = tanhfast(acc[m][2][reg] + bg2);
            float cc = fv * c1 + iv * gv;
            float ov = sigm(acc[m][3][reg] + bo2 + cc * pwo);
            out[off] = ov * tanhfast(cc);
            out[HU + off] = cc;
        }
    }
}

extern "C" void kernel_launch(void* const* d_in, const int* in_sizes, int n_in,
                              void* d_out, int out_size, void* d_ws, size_t ws_size,
                              hipStream_t stream) {
    const float* x    = (const float*)d_in[0];
    const float* h    = (const float*)d_in[1];
    const float* c    = (const float*)d_in[2];
    const float* W    = (const float*)d_in[3];
    const float* R    = (const float*)d_in[4];
    const float* pw   = (const float*)d_in[5];
    const float* bias = (const float*)d_in[6];
    float* out = (float*)d_out;

    unsigned short* xh  = (unsigned short*)d_ws;                        // 33,554,432 B
    unsigned short* btw = (unsigned short*)((char*)d_ws + 33554432u);   // + 4,194,304 B

    prep<<<10240, 256, 0, stream>>>(x, h, W, R, xh, btw);
    lstm_main<<<512, 512, 0, stream>>>(xh, btw, c, pw, bias, out);
}